// Round 2
// baseline (910.263 us; speedup 1.0000x reference)
//
#include <hip/hip_runtime.h>
#include <hip/hip_bf16.h>
#include <math.h>

// align = einsum('bsh,bh->bs', enc, states)/512; w = softmax(align, axis=1);
// ctx = einsum('bsh,bs->bh', enc, w).  B=32, S=8192, H=512, fp32.
// enc = 512 MiB > L3 -> single fused streaming pass (online softmax), partials
// combined in a parallel second kernel.
//
// This round: pass1 processes rows in groups of 4 — 8 float4 loads issued per
// group (double-buffered in STATICALLY-NAMED registers), 4 independent dots,
// interleaved butterfly (6 steps pipelined across 4 rows), one unconditional
// fused rescale per group. Removes the per-row serial chain from the
// bytes-retire path; pass1 should be pure HBM-bound (~95 us for 512 MiB).

#define BB 32
#define SS 8192
#define HH 512
#define NB 64              // blocks per batch
#define WPB 4              // waves per block
#define NP (NB * WPB)      // partials per batch = 256
#define RPW (SS / NP)      // rows per wave = 32
#define GP 4               // rows per group
#define NG (RPW / GP)      // groups per wave = 8
#define WCH 8              // pass2 chunks per batch

__global__ __launch_bounds__(256, 4) void attn_pass1(
    const float* __restrict__ states, const float* __restrict__ enc,
    float* __restrict__ align, float* __restrict__ pm,
    float* __restrict__ pl, float* __restrict__ pC)
{
    const int b     = blockIdx.x >> 6;       // / NB
    const int chunk = blockIdx.x & (NB - 1);
    const int lane  = threadIdx.x & 63;
    const int wv    = threadIdx.x >> 6;
    const int p     = chunk * WPB + wv;      // partial index within batch, 0..255

    // states fragment: lane l owns h in [4l,4l+4) and [256+4l,260+4l)
    const float4* st = (const float4*)(states + (size_t)b * HH);
    const float4 sh0 = st[lane];
    const float4 sh1 = st[lane + 64];

    // this wave's 32 rows start here; row r = float4s [r*128, r*128+128)
    const float4* rp = (const float4*)(enc + ((size_t)b * SS + (size_t)p * RPW) * HH);

    float  m = -1e30f, l = 0.0f;
    float4 c0 = make_float4(0.f, 0.f, 0.f, 0.f);
    float4 c1 = make_float4(0.f, 0.f, 0.f, 0.f);
    float  my_a = 0.0f;                      // lane r keeps align of local row r (r < RPW)

    // group buffers: 4 rows x 2 float4, two static buffers A / B (no runtime
    // indexing -> stays in VGPRs, ~64 regs data)
    float4 A0,A1,A2,A3,A4,A5,A6,A7;
    float4 B0,B1,B2,B3,B4,B5,B6,B7;

#define LOADG(P0,P1,P2,P3,P4,P5,P6,P7, g) do {                        \
        const float4* q = rp + (size_t)(g) * (GP * 128) + lane;       \
        P0 = q[0];   P1 = q[64];                                      \
        P2 = q[128]; P3 = q[192];                                     \
        P4 = q[256]; P5 = q[320];                                     \
        P6 = q[384]; P7 = q[448];                                     \
    } while (0)

#define DOT8(u, v) ((u).x*sh0.x + (u).y*sh0.y + (u).z*sh0.z + (u).w*sh0.w \
                  + (v).x*sh1.x + (v).y*sh1.y + (v).z*sh1.z + (v).w*sh1.w)

#define PROCG(P0,P1,P2,P3,P4,P5,P6,P7, g) do {                        \
        float d0 = DOT8(P0, P1);                                      \
        float d1 = DOT8(P2, P3);                                      \
        float d2 = DOT8(P4, P5);                                      \
        float d3 = DOT8(P6, P7);                                      \
        _Pragma("unroll")                                             \
        for (int off = 1; off < 64; off <<= 1) {                      \
            d0 += __shfl_xor(d0, off, 64);                            \
            d1 += __shfl_xor(d1, off, 64);                            \
            d2 += __shfl_xor(d2, off, 64);                            \
            d3 += __shfl_xor(d3, off, 64);                            \
        }                                                             \
        float a0 = d0 * (1.0f / 512.0f);                              \
        float a1 = d1 * (1.0f / 512.0f);                              \
        float a2 = d2 * (1.0f / 512.0f);                              \
        float a3 = d3 * (1.0f / 512.0f);                              \
        const int rbase = (g) * GP;                                   \
        my_a = (lane == rbase + 0) ? a0 : my_a;                       \
        my_a = (lane == rbase + 1) ? a1 : my_a;                       \
        my_a = (lane == rbase + 2) ? a2 : my_a;                       \
        my_a = (lane == rbase + 3) ? a3 : my_a;                       \
        float mg = fmaxf(fmaxf(a0, a1), fmaxf(a2, a3));               \
        float mn = fmaxf(m, mg);                                      \
        float sc = __expf(m - mn);      /* ==0 on first group */      \
        float p0 = __expf(a0 - mn);                                   \
        float p1 = __expf(a1 - mn);                                   \
        float p2 = __expf(a2 - mn);                                   \
        float p3 = __expf(a3 - mn);                                   \
        l = fmaf(l, sc, (p0 + p1) + (p2 + p3));                       \
        float acc;                                                    \
        acc = p0*P0.x; acc = fmaf(p1,P2.x,acc); acc = fmaf(p2,P4.x,acc); acc = fmaf(p3,P6.x,acc); c0.x = fmaf(c0.x, sc, acc); \
        acc = p0*P0.y; acc = fmaf(p1,P2.y,acc); acc = fmaf(p2,P4.y,acc); acc = fmaf(p3,P6.y,acc); c0.y = fmaf(c0.y, sc, acc); \
        acc = p0*P0.z; acc = fmaf(p1,P2.z,acc); acc = fmaf(p2,P4.z,acc); acc = fmaf(p3,P6.z,acc); c0.z = fmaf(c0.z, sc, acc); \
        acc = p0*P0.w; acc = fmaf(p1,P2.w,acc); acc = fmaf(p2,P4.w,acc); acc = fmaf(p3,P6.w,acc); c0.w = fmaf(c0.w, sc, acc); \
        acc = p0*P1.x; acc = fmaf(p1,P3.x,acc); acc = fmaf(p2,P5.x,acc); acc = fmaf(p3,P7.x,acc); c1.x = fmaf(c1.x, sc, acc); \
        acc = p0*P1.y; acc = fmaf(p1,P3.y,acc); acc = fmaf(p2,P5.y,acc); acc = fmaf(p3,P7.y,acc); c1.y = fmaf(c1.y, sc, acc); \
        acc = p0*P1.z; acc = fmaf(p1,P3.z,acc); acc = fmaf(p2,P5.z,acc); acc = fmaf(p3,P7.z,acc); c1.z = fmaf(c1.z, sc, acc); \
        acc = p0*P1.w; acc = fmaf(p1,P3.w,acc); acc = fmaf(p2,P5.w,acc); acc = fmaf(p3,P7.w,acc); c1.w = fmaf(c1.w, sc, acc); \
        m = mn;                                                       \
    } while (0)

    LOADG(A0,A1,A2,A3,A4,A5,A6,A7, 0);
    #pragma unroll
    for (int g = 0; g < NG; g += 2) {
        LOADG(B0,B1,B2,B3,B4,B5,B6,B7, g + 1);
        PROCG(A0,A1,A2,A3,A4,A5,A6,A7, g);
        if (g + 2 < NG)
            LOADG(A0,A1,A2,A3,A4,A5,A6,A7, g + 2);
        PROCG(B0,B1,B2,B3,B4,B5,B6,B7, g + 1);
    }

#undef LOADG
#undef DOT8
#undef PROCG

    if (lane < RPW)
        align[(size_t)b * SS + (size_t)p * RPW + lane] = my_a;
    if (lane == 0) {
        pm[b * NP + p] = m;
        pl[b * NP + p] = l;
    }
    float4* Cp = (float4*)(pC + (size_t)(b * NP + p) * HH);
    Cp[lane]      = c0;
    Cp[lane + 64] = c1;
}

// grid = BB * WCH = 256 blocks. Each block: redundant M/L reduce over the 256
// partials (cheap), then 1/8 of the context combine (float4) + 1/8 of the
// weights write (float4).
__global__ __launch_bounds__(256) void attn_pass2(
    const float* __restrict__ align, const float* __restrict__ pm,
    const float* __restrict__ pl, const float* __restrict__ pC,
    float* __restrict__ out_ctx, float* __restrict__ out_w)
{
    const int b     = blockIdx.x >> 3;      // / WCH
    const int chunk = blockIdx.x & (WCH - 1);
    const int t     = threadIdx.x;
    const int lane  = t & 63;
    const int wv    = t >> 6;

    __shared__ float  s_w[NP];
    __shared__ float  s_red[8];
    __shared__ float  s_bcast[2];
    __shared__ float4 s_part[256];

    // --- global softmax stats (redundant per block; 256 partials) ---
    float pmv = pm[b * NP + t];             // NP == blockDim.x == 256
    float plv = pl[b * NP + t];

    float mx = pmv;
    #pragma unroll
    for (int off = 1; off < 64; off <<= 1)
        mx = fmaxf(mx, __shfl_xor(mx, off, 64));
    if (lane == 0) s_red[wv] = mx;
    __syncthreads();
    if (t == 0)
        s_bcast[0] = fmaxf(fmaxf(s_red[0], s_red[1]), fmaxf(s_red[2], s_red[3]));
    __syncthreads();
    const float M = s_bcast[0];

    float swv = __expf(pmv - M);
    s_w[t] = swv;
    float Lp = swv * plv;
    #pragma unroll
    for (int off = 1; off < 64; off <<= 1)
        Lp += __shfl_xor(Lp, off, 64);
    if (lane == 0) s_red[wv] = Lp;
    __syncthreads();
    if (t == 0)
        s_bcast[1] = 1.0f / (s_red[0] + s_red[1] + s_red[2] + s_red[3]);
    __syncthreads();
    const float invL = s_bcast[1];

    // --- context combine: this block owns h-range [chunk*64, chunk*64+64) ---
    {
        const int slot = t & 15;            // float4 slot within the 64-col range
        const int pg   = t >> 4;            // 16 p-groups
        const float4* Cb4 = (const float4*)(pC + (size_t)b * NP * HH);
        const int colbase = chunk * 16 + slot;   // float4 column index (of 128)
        float4 acc = make_float4(0.f, 0.f, 0.f, 0.f);
        #pragma unroll 4
        for (int p = pg; p < NP; p += 16) {
            float  w = s_w[p];
            float4 v = Cb4[(size_t)p * 128 + colbase];
            acc.x = fmaf(w, v.x, acc.x);
            acc.y = fmaf(w, v.y, acc.y);
            acc.z = fmaf(w, v.z, acc.z);
            acc.w = fmaf(w, v.w, acc.w);
        }
        s_part[t] = acc;
        __syncthreads();
        if (t < 16) {
            float4 tot = make_float4(0.f, 0.f, 0.f, 0.f);
            #pragma unroll
            for (int g = 0; g < 16; ++g) {
                float4 v = s_part[g * 16 + t];
                tot.x += v.x; tot.y += v.y; tot.z += v.z; tot.w += v.w;
            }
            float4* oc4 = (float4*)(out_ctx + (size_t)b * HH);
            oc4[chunk * 16 + t] = make_float4(tot.x * invL, tot.y * invL,
                                              tot.z * invL, tot.w * invL);
        }
    }

    // --- weights: this block owns s-range [chunk*1024, chunk*1024+1024) ---
    {
        const float4* al4 = (const float4*)(align + (size_t)b * SS + chunk * 1024);
        float4*       ow4 = (float4*)(out_w + (size_t)b * SS + chunk * 1024);
        float4 v = al4[t];                  // 256 threads * 4 = 1024 floats
        ow4[t] = make_float4(__expf(v.x - M) * invL, __expf(v.y - M) * invL,
                             __expf(v.z - M) * invL, __expf(v.w - M) * invL);
    }
}

extern "C" void kernel_launch(void* const* d_in, const int* in_sizes, int n_in,
                              void* d_out, int out_size, void* d_ws, size_t ws_size,
                              hipStream_t stream) {
    const float* states = (const float*)d_in[0];   // (32, 512)
    const float* enc    = (const float*)d_in[1];   // (32, 8192, 512)

    float* out_ctx = (float*)d_out;                    // 32*512
    float* out_w   = (float*)d_out + (size_t)BB * HH;  // 32*8192

    // workspace (floats): align[B*S] | pm[B*NP] | pl[B*NP] | pC[B*NP*H]  (~18 MB)
    float* ws_align = (float*)d_ws;
    float* ws_pm    = ws_align + (size_t)BB * SS;
    float* ws_pl    = ws_pm    + (size_t)BB * NP;
    float* ws_pC    = ws_pl    + (size_t)BB * NP;

    attn_pass1<<<BB * NB, 256, 0, stream>>>(states, enc, ws_align, ws_pm, ws_pl, ws_pC);
    attn_pass2<<<BB * WCH, 256, 0, stream>>>(ws_align, ws_pm, ws_pl, ws_pC, out_ctx, out_w);
}

// Round 3
// 685.290 us; speedup vs baseline: 1.3283x; 1.3283x over previous
//
#include <hip/hip_runtime.h>
#include <hip/hip_bf16.h>
#include <math.h>

// align = einsum('bsh,bh->bs', enc, states)/512; w = softmax(align, axis=1);
// ctx = einsum('bsh,bs->bh', enc, w).  B=32, S=8192, H=512, fp32.
// enc = 512 MiB > L3 -> single fused streaming pass (online softmax), partials
// combined in a parallel second kernel.
//
// Round-2 post-mortem: VGPR_Count=64 + WRITE_SIZE=605MB (logical 18MB) = the
// full-unrolled group loop blew past the 128-reg budget and spilled every
// group buffer to scratch. Fix this round:
//   - __launch_bounds__(256, 2): 256-VGPR budget, ~120 needed -> no spill.
//   - #pragma unroll 1 on the group loop: keep the A/B double-buffer pipeline
//     exactly as written instead of letting the scheduler hoist 4 iterations.

#define BB 32
#define SS 8192
#define HH 512
#define NB 64              // blocks per batch
#define WPB 4              // waves per block
#define NP (NB * WPB)      // partials per batch = 256
#define RPW (SS / NP)      // rows per wave = 32
#define GP 4               // rows per group
#define NG (RPW / GP)      // groups per wave = 8
#define WCH 8              // pass2 chunks per batch

__global__ __launch_bounds__(256, 2) void attn_pass1(
    const float* __restrict__ states, const float* __restrict__ enc,
    float* __restrict__ align, float* __restrict__ pm,
    float* __restrict__ pl, float* __restrict__ pC)
{
    const int b     = blockIdx.x >> 6;       // / NB
    const int chunk = blockIdx.x & (NB - 1);
    const int lane  = threadIdx.x & 63;
    const int wv    = threadIdx.x >> 6;
    const int p     = chunk * WPB + wv;      // partial index within batch, 0..255

    // states fragment: lane l owns h in [4l,4l+4) and [256+4l,260+4l)
    const float4* st = (const float4*)(states + (size_t)b * HH);
    const float4 sh0 = st[lane];
    const float4 sh1 = st[lane + 64];

    // this wave's 32 rows start here; row r = float4s [r*128, r*128+128)
    const float4* rp = (const float4*)(enc + ((size_t)b * SS + (size_t)p * RPW) * HH);

    float  m = -1e30f, l = 0.0f;
    float4 c0 = make_float4(0.f, 0.f, 0.f, 0.f);
    float4 c1 = make_float4(0.f, 0.f, 0.f, 0.f);
    float  my_a = 0.0f;                      // lane r keeps align of local row r (r < RPW)

    // group buffers: 4 rows x 2 float4, two static buffers A / B
    float4 A0,A1,A2,A3,A4,A5,A6,A7;
    float4 B0,B1,B2,B3,B4,B5,B6,B7;

#define LOADG(P0,P1,P2,P3,P4,P5,P6,P7, g) do {                        \
        const float4* q = rp + (size_t)(g) * (GP * 128) + lane;       \
        P0 = q[0];   P1 = q[64];                                      \
        P2 = q[128]; P3 = q[192];                                     \
        P4 = q[256]; P5 = q[320];                                     \
        P6 = q[384]; P7 = q[448];                                     \
    } while (0)

#define DOT8(u, v) ((u).x*sh0.x + (u).y*sh0.y + (u).z*sh0.z + (u).w*sh0.w \
                  + (v).x*sh1.x + (v).y*sh1.y + (v).z*sh1.z + (v).w*sh1.w)

#define PROCG(P0,P1,P2,P3,P4,P5,P6,P7, g) do {                        \
        float d0 = DOT8(P0, P1);                                      \
        float d1 = DOT8(P2, P3);                                      \
        float d2 = DOT8(P4, P5);                                      \
        float d3 = DOT8(P6, P7);                                      \
        _Pragma("unroll")                                             \
        for (int off = 1; off < 64; off <<= 1) {                      \
            d0 += __shfl_xor(d0, off, 64);                            \
            d1 += __shfl_xor(d1, off, 64);                            \
            d2 += __shfl_xor(d2, off, 64);                            \
            d3 += __shfl_xor(d3, off, 64);                            \
        }                                                             \
        float a0 = d0 * (1.0f / 512.0f);                              \
        float a1 = d1 * (1.0f / 512.0f);                              \
        float a2 = d2 * (1.0f / 512.0f);                              \
        float a3 = d3 * (1.0f / 512.0f);                              \
        const int rbase = (g) * GP;                                   \
        my_a = (lane == rbase + 0) ? a0 : my_a;                       \
        my_a = (lane == rbase + 1) ? a1 : my_a;                       \
        my_a = (lane == rbase + 2) ? a2 : my_a;                       \
        my_a = (lane == rbase + 3) ? a3 : my_a;                       \
        float mg = fmaxf(fmaxf(a0, a1), fmaxf(a2, a3));               \
        float mn = fmaxf(m, mg);                                      \
        float sc = __expf(m - mn);      /* ==0 on first group */      \
        float p0 = __expf(a0 - mn);                                   \
        float p1 = __expf(a1 - mn);                                   \
        float p2 = __expf(a2 - mn);                                   \
        float p3 = __expf(a3 - mn);                                   \
        l = fmaf(l, sc, (p0 + p1) + (p2 + p3));                       \
        float acc;                                                    \
        acc = p0*P0.x; acc = fmaf(p1,P2.x,acc); acc = fmaf(p2,P4.x,acc); acc = fmaf(p3,P6.x,acc); c0.x = fmaf(c0.x, sc, acc); \
        acc = p0*P0.y; acc = fmaf(p1,P2.y,acc); acc = fmaf(p2,P4.y,acc); acc = fmaf(p3,P6.y,acc); c0.y = fmaf(c0.y, sc, acc); \
        acc = p0*P0.z; acc = fmaf(p1,P2.z,acc); acc = fmaf(p2,P4.z,acc); acc = fmaf(p3,P6.z,acc); c0.z = fmaf(c0.z, sc, acc); \
        acc = p0*P0.w; acc = fmaf(p1,P2.w,acc); acc = fmaf(p2,P4.w,acc); acc = fmaf(p3,P6.w,acc); c0.w = fmaf(c0.w, sc, acc); \
        acc = p0*P1.x; acc = fmaf(p1,P3.x,acc); acc = fmaf(p2,P5.x,acc); acc = fmaf(p3,P7.x,acc); c1.x = fmaf(c1.x, sc, acc); \
        acc = p0*P1.y; acc = fmaf(p1,P3.y,acc); acc = fmaf(p2,P5.y,acc); acc = fmaf(p3,P7.y,acc); c1.y = fmaf(c1.y, sc, acc); \
        acc = p0*P1.z; acc = fmaf(p1,P3.z,acc); acc = fmaf(p2,P5.z,acc); acc = fmaf(p3,P7.z,acc); c1.z = fmaf(c1.z, sc, acc); \
        acc = p0*P1.w; acc = fmaf(p1,P3.w,acc); acc = fmaf(p2,P5.w,acc); acc = fmaf(p3,P7.w,acc); c1.w = fmaf(c1.w, sc, acc); \
        m = mn;                                                       \
    } while (0)

    LOADG(A0,A1,A2,A3,A4,A5,A6,A7, 0);
    #pragma unroll 1
    for (int g = 0; g < NG; g += 2) {
        LOADG(B0,B1,B2,B3,B4,B5,B6,B7, g + 1);
        PROCG(A0,A1,A2,A3,A4,A5,A6,A7, g);
        if (g + 2 < NG)
            LOADG(A0,A1,A2,A3,A4,A5,A6,A7, g + 2);
        PROCG(B0,B1,B2,B3,B4,B5,B6,B7, g + 1);
    }

#undef LOADG
#undef DOT8
#undef PROCG

    if (lane < RPW)
        align[(size_t)b * SS + (size_t)p * RPW + lane] = my_a;
    if (lane == 0) {
        pm[b * NP + p] = m;
        pl[b * NP + p] = l;
    }
    float4* Cp = (float4*)(pC + (size_t)(b * NP + p) * HH);
    Cp[lane]      = c0;
    Cp[lane + 64] = c1;
}

// grid = BB * WCH = 256 blocks. Each block: redundant M/L reduce over the 256
// partials (cheap), then 1/8 of the context combine (float4) + 1/8 of the
// weights write (float4).
__global__ __launch_bounds__(256) void attn_pass2(
    const float* __restrict__ align, const float* __restrict__ pm,
    const float* __restrict__ pl, const float* __restrict__ pC,
    float* __restrict__ out_ctx, float* __restrict__ out_w)
{
    const int b     = blockIdx.x >> 3;      // / WCH
    const int chunk = blockIdx.x & (WCH - 1);
    const int t     = threadIdx.x;
    const int lane  = t & 63;
    const int wv    = t >> 6;

    __shared__ float  s_w[NP];
    __shared__ float  s_red[8];
    __shared__ float  s_bcast[2];
    __shared__ float4 s_part[256];

    // --- global softmax stats (redundant per block; 256 partials) ---
    float pmv = pm[b * NP + t];             // NP == blockDim.x == 256
    float plv = pl[b * NP + t];

    float mx = pmv;
    #pragma unroll
    for (int off = 1; off < 64; off <<= 1)
        mx = fmaxf(mx, __shfl_xor(mx, off, 64));
    if (lane == 0) s_red[wv] = mx;
    __syncthreads();
    if (t == 0)
        s_bcast[0] = fmaxf(fmaxf(s_red[0], s_red[1]), fmaxf(s_red[2], s_red[3]));
    __syncthreads();
    const float M = s_bcast[0];

    float swv = __expf(pmv - M);
    s_w[t] = swv;
    float Lp = swv * plv;
    #pragma unroll
    for (int off = 1; off < 64; off <<= 1)
        Lp += __shfl_xor(Lp, off, 64);
    if (lane == 0) s_red[wv] = Lp;
    __syncthreads();
    if (t == 0)
        s_bcast[1] = 1.0f / (s_red[0] + s_red[1] + s_red[2] + s_red[3]);
    __syncthreads();
    const float invL = s_bcast[1];

    // --- context combine: this block owns h-range [chunk*64, chunk*64+64) ---
    {
        const int slot = t & 15;            // float4 slot within the 64-col range
        const int pg   = t >> 4;            // 16 p-groups
        const float4* Cb4 = (const float4*)(pC + (size_t)b * NP * HH);
        const int colbase = chunk * 16 + slot;   // float4 column index (of 128)
        float4 acc = make_float4(0.f, 0.f, 0.f, 0.f);
        #pragma unroll 4
        for (int p = pg; p < NP; p += 16) {
            float  w = s_w[p];
            float4 v = Cb4[(size_t)p * 128 + colbase];
            acc.x = fmaf(w, v.x, acc.x);
            acc.y = fmaf(w, v.y, acc.y);
            acc.z = fmaf(w, v.z, acc.z);
            acc.w = fmaf(w, v.w, acc.w);
        }
        s_part[t] = acc;
        __syncthreads();
        if (t < 16) {
            float4 tot = make_float4(0.f, 0.f, 0.f, 0.f);
            #pragma unroll
            for (int g = 0; g < 16; ++g) {
                float4 v = s_part[g * 16 + t];
                tot.x += v.x; tot.y += v.y; tot.z += v.z; tot.w += v.w;
            }
            float4* oc4 = (float4*)(out_ctx + (size_t)b * HH);
            oc4[chunk * 16 + t] = make_float4(tot.x * invL, tot.y * invL,
                                              tot.z * invL, tot.w * invL);
        }
    }

    // --- weights: this block owns s-range [chunk*1024, chunk*1024+1024) ---
    {
        const float4* al4 = (const float4*)(align + (size_t)b * SS + chunk * 1024);
        float4*       ow4 = (float4*)(out_w + (size_t)b * SS + chunk * 1024);
        float4 v = al4[t];                  // 256 threads * 4 = 1024 floats
        ow4[t] = make_float4(__expf(v.x - M) * invL, __expf(v.y - M) * invL,
                             __expf(v.z - M) * invL, __expf(v.w - M) * invL);
    }
}

extern "C" void kernel_launch(void* const* d_in, const int* in_sizes, int n_in,
                              void* d_out, int out_size, void* d_ws, size_t ws_size,
                              hipStream_t stream) {
    const float* states = (const float*)d_in[0];   // (32, 512)
    const float* enc    = (const float*)d_in[1];   // (32, 8192, 512)

    float* out_ctx = (float*)d_out;                    // 32*512
    float* out_w   = (float*)d_out + (size_t)BB * HH;  // 32*8192

    // workspace (floats): align[B*S] | pm[B*NP] | pl[B*NP] | pC[B*NP*H]  (~18 MB)
    float* ws_align = (float*)d_ws;
    float* ws_pm    = ws_align + (size_t)BB * SS;
    float* ws_pl    = ws_pm    + (size_t)BB * NP;
    float* ws_pC    = ws_pl    + (size_t)BB * NP;

    attn_pass1<<<BB * NB, 256, 0, stream>>>(states, enc, ws_align, ws_pm, ws_pl, ws_pC);
    attn_pass2<<<BB * WCH, 256, 0, stream>>>(ws_align, ws_pm, ws_pl, ws_pC, out_ctx, out_w);
}

// Round 4
// 668.837 us; speedup vs baseline: 1.3610x; 1.0246x over previous
//
#include <hip/hip_runtime.h>
#include <hip/hip_bf16.h>
#include <math.h>

// align = einsum('bsh,bh->bs', enc, states)/512; w = softmax(align, axis=1);
// ctx = einsum('bsh,bs->bh', enc, w).  B=32, S=8192, H=512, fp32.
// enc = 512 MiB > L3 -> single fused streaming pass (online softmax), partials
// combined in a parallel second kernel.
//
// Round-3 post-mortem: pass1 ~159us (3.5 TB/s read) across THREE different
// structures (occ 2..6, in-flight 2..16KB/wave) -> limiter is supply-side in
// the read path, not demand. Single-variable test this round: non-temporal
// (nt) loads for the enc stream (512 MiB, zero reuse) to skip cache
// allocation on fill. Everything else identical to round 3.

#define BB 32
#define SS 8192
#define HH 512
#define NB 64              // blocks per batch
#define WPB 4              // waves per block
#define NP (NB * WPB)      // partials per batch = 256
#define RPW (SS / NP)      // rows per wave = 32
#define GP 4               // rows per group
#define NG (RPW / GP)      // groups per wave = 8
#define WCH 8              // pass2 chunks per batch

typedef float f4 __attribute__((ext_vector_type(4)));

__global__ __launch_bounds__(256, 2) void attn_pass1(
    const float* __restrict__ states, const float* __restrict__ enc,
    float* __restrict__ align, float* __restrict__ pm,
    float* __restrict__ pl, float* __restrict__ pC)
{
    const int b     = blockIdx.x >> 6;       // / NB
    const int chunk = blockIdx.x & (NB - 1);
    const int lane  = threadIdx.x & 63;
    const int wv    = threadIdx.x >> 6;
    const int p     = chunk * WPB + wv;      // partial index within batch, 0..255

    // states fragment: lane l owns h in [4l,4l+4) and [256+4l,260+4l)
    const f4* st = (const f4*)(states + (size_t)b * HH);
    const f4 sh0 = st[lane];
    const f4 sh1 = st[lane + 64];

    // this wave's 32 rows start here; row r = float4s [r*128, r*128+128)
    const f4* rp = (const f4*)(enc + ((size_t)b * SS + (size_t)p * RPW) * HH);

    float m = -1e30f, l = 0.0f;
    f4 c0 = (f4)(0.0f);
    f4 c1 = (f4)(0.0f);
    float my_a = 0.0f;                       // lane r keeps align of local row r (r < RPW)

    // group buffers: 4 rows x 2 f4, two static buffers A / B
    f4 A0,A1,A2,A3,A4,A5,A6,A7;
    f4 B0,B1,B2,B3,B4,B5,B6,B7;

#define LOADG(P0,P1,P2,P3,P4,P5,P6,P7, g) do {                        \
        const f4* q = rp + (size_t)(g) * (GP * 128) + lane;           \
        P0 = __builtin_nontemporal_load(q);                           \
        P1 = __builtin_nontemporal_load(q + 64);                      \
        P2 = __builtin_nontemporal_load(q + 128);                     \
        P3 = __builtin_nontemporal_load(q + 192);                     \
        P4 = __builtin_nontemporal_load(q + 256);                     \
        P5 = __builtin_nontemporal_load(q + 320);                     \
        P6 = __builtin_nontemporal_load(q + 384);                     \
        P7 = __builtin_nontemporal_load(q + 448);                     \
    } while (0)

#define DOT8(u, v) ((u).x*sh0.x + (u).y*sh0.y + (u).z*sh0.z + (u).w*sh0.w \
                  + (v).x*sh1.x + (v).y*sh1.y + (v).z*sh1.z + (v).w*sh1.w)

#define PROCG(P0,P1,P2,P3,P4,P5,P6,P7, g) do {                        \
        float d0 = DOT8(P0, P1);                                      \
        float d1 = DOT8(P2, P3);                                      \
        float d2 = DOT8(P4, P5);                                      \
        float d3 = DOT8(P6, P7);                                      \
        _Pragma("unroll")                                             \
        for (int off = 1; off < 64; off <<= 1) {                      \
            d0 += __shfl_xor(d0, off, 64);                            \
            d1 += __shfl_xor(d1, off, 64);                            \
            d2 += __shfl_xor(d2, off, 64);                            \
            d3 += __shfl_xor(d3, off, 64);                            \
        }                                                             \
        float a0 = d0 * (1.0f / 512.0f);                              \
        float a1 = d1 * (1.0f / 512.0f);                              \
        float a2 = d2 * (1.0f / 512.0f);                              \
        float a3 = d3 * (1.0f / 512.0f);                              \
        const int rbase = (g) * GP;                                   \
        my_a = (lane == rbase + 0) ? a0 : my_a;                       \
        my_a = (lane == rbase + 1) ? a1 : my_a;                       \
        my_a = (lane == rbase + 2) ? a2 : my_a;                       \
        my_a = (lane == rbase + 3) ? a3 : my_a;                       \
        float mg = fmaxf(fmaxf(a0, a1), fmaxf(a2, a3));               \
        float mn = fmaxf(m, mg);                                      \
        float sc = __expf(m - mn);      /* ==0 on first group */      \
        float p0 = __expf(a0 - mn);                                   \
        float p1 = __expf(a1 - mn);                                   \
        float p2 = __expf(a2 - mn);                                   \
        float p3 = __expf(a3 - mn);                                   \
        l = fmaf(l, sc, (p0 + p1) + (p2 + p3));                       \
        float acc;                                                    \
        acc = p0*P0.x; acc = fmaf(p1,P2.x,acc); acc = fmaf(p2,P4.x,acc); acc = fmaf(p3,P6.x,acc); c0.x = fmaf(c0.x, sc, acc); \
        acc = p0*P0.y; acc = fmaf(p1,P2.y,acc); acc = fmaf(p2,P4.y,acc); acc = fmaf(p3,P6.y,acc); c0.y = fmaf(c0.y, sc, acc); \
        acc = p0*P0.z; acc = fmaf(p1,P2.z,acc); acc = fmaf(p2,P4.z,acc); acc = fmaf(p3,P6.z,acc); c0.z = fmaf(c0.z, sc, acc); \
        acc = p0*P0.w; acc = fmaf(p1,P2.w,acc); acc = fmaf(p2,P4.w,acc); acc = fmaf(p3,P6.w,acc); c0.w = fmaf(c0.w, sc, acc); \
        acc = p0*P1.x; acc = fmaf(p1,P3.x,acc); acc = fmaf(p2,P5.x,acc); acc = fmaf(p3,P7.x,acc); c1.x = fmaf(c1.x, sc, acc); \
        acc = p0*P1.y; acc = fmaf(p1,P3.y,acc); acc = fmaf(p2,P5.y,acc); acc = fmaf(p3,P7.y,acc); c1.y = fmaf(c1.y, sc, acc); \
        acc = p0*P1.z; acc = fmaf(p1,P3.z,acc); acc = fmaf(p2,P5.z,acc); acc = fmaf(p3,P7.z,acc); c1.z = fmaf(c1.z, sc, acc); \
        acc = p0*P1.w; acc = fmaf(p1,P3.w,acc); acc = fmaf(p2,P5.w,acc); acc = fmaf(p3,P7.w,acc); c1.w = fmaf(c1.w, sc, acc); \
        m = mn;                                                       \
    } while (0)

    LOADG(A0,A1,A2,A3,A4,A5,A6,A7, 0);
    #pragma unroll 1
    for (int g = 0; g < NG; g += 2) {
        LOADG(B0,B1,B2,B3,B4,B5,B6,B7, g + 1);
        PROCG(A0,A1,A2,A3,A4,A5,A6,A7, g);
        if (g + 2 < NG)
            LOADG(A0,A1,A2,A3,A4,A5,A6,A7, g + 2);
        PROCG(B0,B1,B2,B3,B4,B5,B6,B7, g + 1);
    }

#undef LOADG
#undef DOT8
#undef PROCG

    if (lane < RPW)
        align[(size_t)b * SS + (size_t)p * RPW + lane] = my_a;
    if (lane == 0) {
        pm[b * NP + p] = m;
        pl[b * NP + p] = l;
    }
    // pC/align stay normal (cached) stores: pass2 re-reads them immediately.
    f4* Cp = (f4*)(pC + (size_t)(b * NP + p) * HH);
    Cp[lane]      = c0;
    Cp[lane + 64] = c1;
}

// grid = BB * WCH = 256 blocks. Each block: redundant M/L reduce over the 256
// partials (cheap), then 1/8 of the context combine (float4) + 1/8 of the
// weights write (float4).
__global__ __launch_bounds__(256) void attn_pass2(
    const float* __restrict__ align, const float* __restrict__ pm,
    const float* __restrict__ pl, const float* __restrict__ pC,
    float* __restrict__ out_ctx, float* __restrict__ out_w)
{
    const int b     = blockIdx.x >> 3;      // / WCH
    const int chunk = blockIdx.x & (WCH - 1);
    const int t     = threadIdx.x;
    const int lane  = t & 63;
    const int wv    = t >> 6;

    __shared__ float  s_w[NP];
    __shared__ float  s_red[8];
    __shared__ float  s_bcast[2];
    __shared__ float4 s_part[256];

    // --- global softmax stats (redundant per block; 256 partials) ---
    float pmv = pm[b * NP + t];             // NP == blockDim.x == 256
    float plv = pl[b * NP + t];

    float mx = pmv;
    #pragma unroll
    for (int off = 1; off < 64; off <<= 1)
        mx = fmaxf(mx, __shfl_xor(mx, off, 64));
    if (lane == 0) s_red[wv] = mx;
    __syncthreads();
    if (t == 0)
        s_bcast[0] = fmaxf(fmaxf(s_red[0], s_red[1]), fmaxf(s_red[2], s_red[3]));
    __syncthreads();
    const float M = s_bcast[0];

    float swv = __expf(pmv - M);
    s_w[t] = swv;
    float Lp = swv * plv;
    #pragma unroll
    for (int off = 1; off < 64; off <<= 1)
        Lp += __shfl_xor(Lp, off, 64);
    if (lane == 0) s_red[wv] = Lp;
    __syncthreads();
    if (t == 0)
        s_bcast[1] = 1.0f / (s_red[0] + s_red[1] + s_red[2] + s_red[3]);
    __syncthreads();
    const float invL = s_bcast[1];

    // --- context combine: this block owns h-range [chunk*64, chunk*64+64) ---
    {
        const int slot = t & 15;            // float4 slot within the 64-col range
        const int pg   = t >> 4;            // 16 p-groups
        const float4* Cb4 = (const float4*)(pC + (size_t)b * NP * HH);
        const int colbase = chunk * 16 + slot;   // float4 column index (of 128)
        float4 acc = make_float4(0.f, 0.f, 0.f, 0.f);
        #pragma unroll 4
        for (int p = pg; p < NP; p += 16) {
            float  w = s_w[p];
            float4 v = Cb4[(size_t)p * 128 + colbase];
            acc.x = fmaf(w, v.x, acc.x);
            acc.y = fmaf(w, v.y, acc.y);
            acc.z = fmaf(w, v.z, acc.z);
            acc.w = fmaf(w, v.w, acc.w);
        }
        s_part[t] = acc;
        __syncthreads();
        if (t < 16) {
            float4 tot = make_float4(0.f, 0.f, 0.f, 0.f);
            #pragma unroll
            for (int g = 0; g < 16; ++g) {
                float4 v = s_part[g * 16 + t];
                tot.x += v.x; tot.y += v.y; tot.z += v.z; tot.w += v.w;
            }
            float4* oc4 = (float4*)(out_ctx + (size_t)b * HH);
            oc4[chunk * 16 + t] = make_float4(tot.x * invL, tot.y * invL,
                                              tot.z * invL, tot.w * invL);
        }
    }

    // --- weights: this block owns s-range [chunk*1024, chunk*1024+1024) ---
    {
        const float4* al4 = (const float4*)(align + (size_t)b * SS + chunk * 1024);
        float4*       ow4 = (float4*)(out_w + (size_t)b * SS + chunk * 1024);
        float4 v = al4[t];                  // 256 threads * 4 = 1024 floats
        ow4[t] = make_float4(__expf(v.x - M) * invL, __expf(v.y - M) * invL,
                             __expf(v.z - M) * invL, __expf(v.w - M) * invL);
    }
}

extern "C" void kernel_launch(void* const* d_in, const int* in_sizes, int n_in,
                              void* d_out, int out_size, void* d_ws, size_t ws_size,
                              hipStream_t stream) {
    const float* states = (const float*)d_in[0];   // (32, 512)
    const float* enc    = (const float*)d_in[1];   // (32, 8192, 512)

    float* out_ctx = (float*)d_out;                    // 32*512
    float* out_w   = (float*)d_out + (size_t)BB * HH;  // 32*8192

    // workspace (floats): align[B*S] | pm[B*NP] | pl[B*NP] | pC[B*NP*H]  (~18 MB)
    float* ws_align = (float*)d_ws;
    float* ws_pm    = ws_align + (size_t)BB * SS;
    float* ws_pl    = ws_pm    + (size_t)BB * NP;
    float* ws_pC    = ws_pl    + (size_t)BB * NP;

    attn_pass1<<<BB * NB, 256, 0, stream>>>(states, enc, ws_align, ws_pm, ws_pl, ws_pC);
    attn_pass2<<<BB * WCH, 256, 0, stream>>>(ws_align, ws_pm, ws_pl, ws_pC, out_ctx, out_w);
}